// Round 1
// baseline (215.940 us; speedup 1.0000x reference)
//
#include <hip/hip_runtime.h>
#include <hip/hip_bf16.h>

typedef __attribute__((ext_vector_type(8))) short bf16x8;
typedef __attribute__((ext_vector_type(4))) float f32x4;

#define BM 128
#define BN 128
#define BK 32

__device__ __forceinline__ unsigned short f2bf(float f) {
  unsigned int u = __builtin_bit_cast(unsigned int, f);
  u += 0x7fffu + ((u >> 16) & 1u);
  return (unsigned short)(u >> 16);
}
__device__ __forceinline__ float bf2f(unsigned int h) {
  unsigned int u = h << 16;
  return __builtin_bit_cast(float, u);
}

__device__ __forceinline__ void gload_lds16(const void* g, void* l) {
  __builtin_amdgcn_global_load_lds(
      (const __attribute__((address_space(1))) void*)g,
      (__attribute__((address_space(3))) void*)l, 16, 0, 0);
}

// ---------------------------------------------------------------------------
// NT GEMM: C[m][n] = sum_k A[m][k] * Bt[n][k]   (A, Bt bf16 row-major)
// EPI 0: bf16 out row-major, (acc+bias)*scale
// EPI 1: bf16 out transposed per 2048-row batch: Vt[b][n][s] = C[b*2048+s][n] + bias[n]
// EPI 2: bf16 out row-major (scores), no bias
// EPI 3: f32 out row-major (final), no bias
// ---------------------------------------------------------------------------
template <int EPI>
__global__ __launch_bounds__(256, 2) void gemm_nt(
    const unsigned short* __restrict__ Abase,
    const unsigned short* __restrict__ Btbase,
    const float* __restrict__ bias, void* __restrict__ Cbase, int Kd, int ldc,
    float scale, long long strideAz, long long strideBz, long long strideCz) {
  __shared__ unsigned short As[BM * BK];
  __shared__ unsigned short Bs[BN * BK];

  const int bm = blockIdx.y * BM;
  const int bn = blockIdx.x * BN;
  const int z = blockIdx.z;
  const unsigned short* A = Abase + (size_t)z * strideAz;
  const unsigned short* Bt = Btbase + (size_t)z * strideBz;

  const int tid = threadIdx.x;
  const int w = tid >> 6, l = tid & 63;
  const int wr = w >> 1, wc = w & 1;
  const int lq = l >> 4, lr = l & 15;

  // staging: linear LDS slot -> swizzled global source column block
  // slot s (bytes): r = s>>6 (row of [128][32] bf16 tile), c16 = (s>>4)&3
  // stored col block cs = c16 ^ ((r>>1)&3)   (read applies same XOR)
  const int s0 = tid * 16;
  const int r0 = s0 >> 6, c0 = ((s0 >> 4) & 3) ^ ((r0 >> 1) & 3);
  const int s1 = s0 + 4096;
  const int r1 = s1 >> 6, c1 = ((s1 >> 4) & 3) ^ ((r1 >> 1) & 3);

  const unsigned short* gA0 = A + (size_t)(bm + r0) * Kd + c0 * 8;
  const unsigned short* gA1 = A + (size_t)(bm + r1) * Kd + c1 * 8;
  const unsigned short* gB0 = Bt + (size_t)(bn + r0) * Kd + c0 * 8;
  const unsigned short* gB1 = Bt + (size_t)(bn + r1) * Kd + c1 * 8;

  char* lA = (char*)As + w * 1024;
  char* lB = (char*)Bs + w * 1024;

  const int rowA = wr * 64 + lr;
  const int rowB = wc * 64 + lr;
  const char* pA =
      (const char*)As + rowA * 64 + ((lq * 16) ^ (((rowA >> 1) & 3) << 4));
  const char* pB =
      (const char*)Bs + rowB * 64 + ((lq * 16) ^ (((rowB >> 1) & 3) << 4));

  f32x4 acc[4][4] = {};

  for (int k0 = 0; k0 < Kd; k0 += BK) {
    gload_lds16(gA0 + k0, lA);
    gload_lds16(gA1 + k0, lA + 4096);
    gload_lds16(gB0 + k0, lB);
    gload_lds16(gB1 + k0, lB + 4096);
    __syncthreads();  // drains vmcnt (compiler-inserted) before reads
    bf16x8 a[4], b[4];
#pragma unroll
    for (int i = 0; i < 4; ++i) {
      a[i] = *(const bf16x8*)(pA + i * 1024);
      b[i] = *(const bf16x8*)(pB + i * 1024);
    }
#pragma unroll
    for (int mi = 0; mi < 4; ++mi)
#pragma unroll
      for (int ni = 0; ni < 4; ++ni)
        acc[mi][ni] = __builtin_amdgcn_mfma_f32_16x16x32_bf16(
            a[mi], b[ni], acc[mi][ni], 0, 0, 0);
    __syncthreads();
  }

  // Epilogue. C/D frag layout: col = lane&15, row = (lane>>4)*4 + e  [m89]
  if constexpr (EPI == 0) {
    unsigned short* Co = (unsigned short*)Cbase;
#pragma unroll
    for (int ni = 0; ni < 4; ++ni) {
      const int col = bn + wc * 64 + ni * 16 + lr;
      const float bv = bias[col];
#pragma unroll
      for (int mi = 0; mi < 4; ++mi) {
        const int row = bm + wr * 64 + mi * 16 + lq * 4;
#pragma unroll
        for (int e = 0; e < 4; ++e)
          Co[(size_t)(row + e) * ldc + col] =
              f2bf((acc[mi][ni][e] + bv) * scale);
      }
    }
  } else if constexpr (EPI == 1) {
    unsigned short* Co = (unsigned short*)Cbase;
#pragma unroll
    for (int ni = 0; ni < 4; ++ni) {
      const int col = bn + wc * 64 + ni * 16 + lr;  // output feature d
      const float bv = bias[col];
#pragma unroll
      for (int mi = 0; mi < 4; ++mi) {
        const int m = bm + wr * 64 + mi * 16 + lq * 4;
        const int bb = m >> 11, s = m & 2047;
        ushort4 pk;
        pk.x = f2bf(acc[mi][ni][0] + bv);
        pk.y = f2bf(acc[mi][ni][1] + bv);
        pk.z = f2bf(acc[mi][ni][2] + bv);
        pk.w = f2bf(acc[mi][ni][3] + bv);
        *(ushort4*)&Co[((size_t)bb * 1024 + col) * 2048 + s] = pk;
      }
    }
  } else if constexpr (EPI == 2) {
    unsigned short* Co = (unsigned short*)Cbase + (size_t)z * strideCz;
#pragma unroll
    for (int ni = 0; ni < 4; ++ni) {
      const int col = bn + wc * 64 + ni * 16 + lr;
#pragma unroll
      for (int mi = 0; mi < 4; ++mi) {
        const int row = bm + wr * 64 + mi * 16 + lq * 4;
#pragma unroll
        for (int e = 0; e < 4; ++e)
          Co[(size_t)(row + e) * ldc + col] = f2bf(acc[mi][ni][e]);
      }
    }
  } else {
    float* Co = (float*)Cbase + (size_t)z * strideCz;
#pragma unroll
    for (int ni = 0; ni < 4; ++ni) {
      const int col = bn + wc * 64 + ni * 16 + lr;
#pragma unroll
      for (int mi = 0; mi < 4; ++mi) {
        const int row = bm + wr * 64 + mi * 16 + lq * 4;
#pragma unroll
        for (int e = 0; e < 4; ++e)
          Co[(size_t)(row + e) * ldc + col] = acc[mi][ni][e];
      }
    }
  }
}

// ---------------------------------------------------------------------------
__global__ __launch_bounds__(256) void cvt_x(const float* __restrict__ in,
                                             unsigned short* __restrict__ out) {
  const int i = blockIdx.x * 256 + threadIdx.x;  // 2M threads x 4 elems
  const float4 v = ((const float4*)in)[i];
  ushort4 o;
  o.x = f2bf(v.x);
  o.y = f2bf(v.y);
  o.z = f2bf(v.z);
  o.w = f2bf(v.w);
  ((ushort4*)out)[i] = o;
}

// W [1024 in][1024 out] f32  ->  Wt [1024 out][1024 in] bf16, z selects q/k/v
__global__ void cvt_wt(const float* __restrict__ Wq,
                       const float* __restrict__ Wk,
                       const float* __restrict__ Wv,
                       unsigned short* __restrict__ Wt) {
  __shared__ float s[32][33];
  const float* W = blockIdx.z == 0 ? Wq : (blockIdx.z == 1 ? Wk : Wv);
  unsigned short* O = Wt + (size_t)blockIdx.z * 1048576;
  const int k0 = blockIdx.y * 32, n0 = blockIdx.x * 32;
  s[threadIdx.y][threadIdx.x] =
      W[(size_t)(k0 + threadIdx.y) * 1024 + n0 + threadIdx.x];
  __syncthreads();
  O[(size_t)(n0 + threadIdx.y) * 1024 + k0 + threadIdx.x] =
      f2bf(s[threadIdx.x][threadIdx.y]);
}

// in-place row softmax over bf16 [4][2048][2048]; one block per row
__global__ __launch_bounds__(256) void softmax_rows(
    unsigned short* __restrict__ SP) {
  const size_t base = ((size_t)blockIdx.y * 2048 + blockIdx.x) * 2048;
  unsigned short* p = SP + base;
  const int t = threadIdx.x;
  __shared__ float red[4];

  uint4 u = ((const uint4*)p)[t];  // 8 bf16 per thread
  unsigned int uu[4] = {u.x, u.y, u.z, u.w};
  float f[8];
#pragma unroll
  for (int j = 0; j < 4; ++j) {
    f[2 * j] = bf2f(uu[j] & 0xffffu);
    f[2 * j + 1] = __builtin_bit_cast(float, uu[j] & 0xffff0000u);
  }
  float mx = f[0];
#pragma unroll
  for (int i = 1; i < 8; ++i) mx = fmaxf(mx, f[i]);
#pragma unroll
  for (int o = 32; o; o >>= 1) mx = fmaxf(mx, __shfl_xor(mx, o, 64));
  if ((t & 63) == 0) red[t >> 6] = mx;
  __syncthreads();
  mx = fmaxf(fmaxf(red[0], red[1]), fmaxf(red[2], red[3]));
  __syncthreads();

  float e[8];
  float sum = 0.f;
#pragma unroll
  for (int i = 0; i < 8; ++i) {
    e[i] = __expf(f[i] - mx);
    sum += e[i];
  }
#pragma unroll
  for (int o = 32; o; o >>= 1) sum += __shfl_xor(sum, o, 64);
  if ((t & 63) == 0) red[t >> 6] = sum;
  __syncthreads();
  sum = red[0] + red[1] + red[2] + red[3];
  const float inv = 1.0f / sum;

  uint4 ov;
  unsigned int w0[4];
#pragma unroll
  for (int j = 0; j < 4; ++j) {
    unsigned int lo = f2bf(e[2 * j] * inv);
    unsigned int hi = f2bf(e[2 * j + 1] * inv);
    w0[j] = lo | (hi << 16);
  }
  ov.x = w0[0];
  ov.y = w0[1];
  ov.z = w0[2];
  ov.w = w0[3];
  ((uint4*)p)[t] = ov;
}

// ---------------------------------------------------------------------------
extern "C" void kernel_launch(void* const* d_in, const int* in_sizes, int n_in,
                              void* d_out, int out_size, void* d_ws,
                              size_t ws_size, hipStream_t stream) {
  const float* x = (const float*)d_in[0];
  const float* Wq = (const float*)d_in[1];
  const float* bq = (const float*)d_in[2];
  const float* Wk = (const float*)d_in[3];
  const float* bk = (const float*)d_in[4];
  const float* Wv = (const float*)d_in[5];
  const float* bv = (const float*)d_in[6];
  float* out = (float*)d_out;
  char* ws = (char*)d_ws;

  unsigned short* xb = (unsigned short*)ws;                        // 16 MiB
  unsigned short* Wt = (unsigned short*)(ws + 16777216);           // 6 MiB
  unsigned short* Qb = (unsigned short*)(ws + 23068672);           // 16 MiB
  unsigned short* Kb = Qb + 8388608;                               // 16 MiB
  unsigned short* Vt = Kb + 8388608;                               // 16 MiB
  unsigned short* SP = Vt + 8388608;                               // 32 MiB

  // 1) dtype prep
  cvt_x<<<8192, 256, 0, stream>>>(x, xb);
  cvt_wt<<<dim3(32, 32, 3), dim3(32, 32), 0, stream>>>(Wq, Wk, Wv, Wt);

  // 2) projections: Q scaled by 1/sqrt(1024)=1/32 (exact in bf16)
  gemm_nt<0><<<dim3(8, 64, 1), 256, 0, stream>>>(xb, Wt, bq, Qb, 1024, 1024,
                                                 0.03125f, 0, 0, 0);
  gemm_nt<0><<<dim3(8, 64, 1), 256, 0, stream>>>(xb, Wt + 1048576, bk, Kb, 1024,
                                                 1024, 1.0f, 0, 0, 0);
  gemm_nt<1><<<dim3(8, 64, 1), 256, 0, stream>>>(xb, Wt + 2097152, bv, Vt, 1024,
                                                 0, 1.0f, 0, 0, 0);

  // 3) scores = Qs . K^T  (bf16 out, per batch via z)
  gemm_nt<2><<<dim3(16, 16, 4), 256, 0, stream>>>(
      Qb, Kb, nullptr, SP, 1024, 2048, 1.0f, 2097152LL, 2097152LL, 4194304LL);

  // 4) softmax in place
  softmax_rows<<<dim3(2048, 4), 256, 0, stream>>>(SP);

  // 5) out = P . V   (A = P, Bt = Vt)
  gemm_nt<3><<<dim3(8, 16, 4), 256, 0, stream>>>(
      SP, Vt, nullptr, out, 2048, 1024, 1.0f, 4194304LL, 2097152LL, 2097152LL);
}

// Round 2
// 192.491 us; speedup vs baseline: 1.1218x; 1.1218x over previous
//
#include <hip/hip_runtime.h>
#include <hip/hip_bf16.h>

typedef __attribute__((ext_vector_type(8))) short bf16x8;
typedef __attribute__((ext_vector_type(4))) float f32x4;
typedef unsigned short u16;

__device__ __forceinline__ u16 f2bf(float f) {
  unsigned int u = __builtin_bit_cast(unsigned int, f);
  u += 0x7fffu + ((u >> 16) & 1u);
  return (u16)(u >> 16);
}
__device__ __forceinline__ float bf2f(unsigned int h) {
  unsigned int u = h << 16;
  return __builtin_bit_cast(float, u);
}

__device__ __forceinline__ void gload_lds16(const void* g, void* l) {
  __builtin_amdgcn_global_load_lds(
      (const __attribute__((address_space(1))) void*)g,
      (__attribute__((address_space(3))) void*)l, 16, 0, 0);
}

#define BAR()                          \
  __builtin_amdgcn_s_barrier();        \
  __builtin_amdgcn_sched_barrier(0)

// ---------------------------------------------------------------------------
// 8-phase counted-vmcnt NT GEMM (T3+T4+T5).  C[m][n] = sum_k A[m][k]*Bt[n][k].
// BN fixed at 256; BM in {128,256}. 512 threads = 8 waves (2 wr x 4 wc).
// Per-wave output BM/2 x 64. BK=64 as 2 k-halves; 4 phases per K-tile.
// LDS units [rows][32] bf16, 16B-block swizzle cb ^= (row>>1)&3 (0-conflict,
// verified round 1). Staged via pre-swizzled global source (linear LDS dest).
// EPI 0: fused QKV projection (Q:*1/32+bq, K:+bk, V:+bv transposed to Vt)
// EPI 2: bf16 row-major out (scores)        EPI 3: f32 row-major out (final)
// ---------------------------------------------------------------------------
template <int BM, int BN, int EPI>
__global__ __launch_bounds__(512, 2) void gemm8(
    const u16* __restrict__ Abase, const u16* __restrict__ Btbase,
    const float* __restrict__ bq, const float* __restrict__ bk,
    const float* __restrict__ bv, void* __restrict__ out0,
    void* __restrict__ out1, void* __restrict__ out2, int Kd, int ldc,
    long long sAz, long long sBz, long long sCz) {
  static_assert(BN == 256, "");
  constexpr int AU = BM * 64;          // bytes per A k-half unit
  constexpr int BU = BN * 64;
  constexpr int HALF = 2 * AU + 2 * BU;
  constexpr int MF = BM / 32;          // m-frags per wave
  constexpr int AL = BM / 128;         // gloads/thread per A unit
  constexpr int BL = BN / 128;
  constexpr int SV = 2 * AL + BL;      // steady-state vmcnt
  __shared__ char lds[2 * HALF];

  const int tid = threadIdx.x;
  const int w = tid >> 6, l = tid & 63;
  const int wr = w >> 2, wc = w & 3;
  const int lq = l >> 4, lr = l & 15;
  const int bm = blockIdx.y * BM, bn = blockIdx.x * BN;
  const int z = blockIdx.z;
  const u16* A = Abase + (size_t)z * sAz;
  const u16* Bt = Btbase + (size_t)z * sBz;
  const int NT = Kd >> 6;

  // staging source (per thread): dest slot tid*16 (+8192 for second load)
  const int sr = tid >> 2;                       // dest row
  const int scb = (tid & 3) ^ ((sr >> 1) & 3);   // swizzled 16B col block
  const u16* gA = A + (size_t)(bm + sr) * Kd + scb * 8;
  const u16* gB = Bt + (size_t)(bn + sr) * Kd + scb * 8;

  auto stageA = [&](int buf, int kh, int t) {
    const int koff = t * 64 + kh * 32;
    char* dst = lds + buf * HALF + kh * AU + w * 1024;
    gload_lds16(gA + koff, dst);
    if constexpr (AL == 2)
      gload_lds16(gA + (size_t)128 * Kd + koff, dst + 8192);
  };
  auto stageB = [&](int buf, int kh, int t) {
    const int koff = t * 64 + kh * 32;
    char* dst = lds + buf * HALF + 2 * AU + kh * BU + w * 1024;
    gload_lds16(gB + koff, dst);
    if constexpr (BL == 2)
      gload_lds16(gB + (size_t)128 * Kd + koff, dst + 8192);
  };

  // fragment read bases (swizzle sel is row-invariant across mi*16: (8mi)&3==0)
  const int rowA = wr * (BM / 2) + lr;
  const int rowB = wc * (BN / 4) + lr;
  const int offA = rowA * 64 + (((lq ^ (rowA >> 1)) & 3) << 4);
  const int offB = rowB * 64 + (((lq ^ (rowB >> 1)) & 3) << 4);

  f32x4 acc[MF][4] = {};
  bf16x8 a[MF], b[2];

  auto rdA = [&](int buf, int kh) {
#pragma unroll
    for (int mi = 0; mi < MF; ++mi)
      a[mi] = *(const bf16x8*)(lds + buf * HALF + kh * AU + offA + mi * 1024);
  };
  auto rdB = [&](int buf, int kh, int nh) {
#pragma unroll
    for (int ni = 0; ni < 2; ++ni)
      b[ni] = *(const bf16x8*)(lds + buf * HALF + 2 * AU + kh * BU + offB +
                               (nh * 2 + ni) * 1024);
  };
  auto mma = [&](int nh) {
    __builtin_amdgcn_s_setprio(1);
#pragma unroll
    for (int mi = 0; mi < MF; ++mi)
#pragma unroll
      for (int ni = 0; ni < 2; ++ni)
        acc[mi][nh * 2 + ni] = __builtin_amdgcn_mfma_f32_16x16x32_bf16(
            a[mi], b[ni], acc[mi][nh * 2 + ni], 0, 0, 0);
    __builtin_amdgcn_s_setprio(0);
  };

  // prologue: T0 all 4 units, T1 first 3 (steady-state in-flight pattern)
  stageA(0, 0, 0);
  stageB(0, 0, 0);
  stageA(0, 1, 0);
  stageB(0, 1, 0);
  if (NT > 1) {
    stageA(1, 0, 1);
    stageB(1, 0, 1);
    stageA(1, 1, 1);
    asm volatile("s_waitcnt vmcnt(%0)" ::"n"(SV) : "memory");
  } else {
    asm volatile("s_waitcnt vmcnt(0)" ::: "memory");
  }
  BAR();

  for (int t = 0; t < NT; ++t) {
    const int buf = t & 1;
    // ph0: k0 x nh0
    rdA(buf, 0);
    rdB(buf, 0, 0);
    if (t + 1 < NT) stageB(buf ^ 1, 1, t + 1);
    BAR();
    mma(0);
    BAR();
    // ph1: k0 x nh1
    rdB(buf, 0, 1);
    if (t + 2 < NT) stageA(buf, 0, t + 2);
    BAR();
    mma(1);
    BAR();
    // ph2: k1 x nh0
    rdA(buf, 1);
    rdB(buf, 1, 0);
    if (t + 2 < NT) stageB(buf, 0, t + 2);
    BAR();
    mma(0);
    BAR();
    // ph3: k1 x nh1 + the once-per-K-tile counted vmcnt
    rdB(buf, 1, 1);
    if (t + 2 < NT) stageA(buf, 1, t + 2);
    BAR();
    mma(1);
    if (t + 2 < NT)
      asm volatile("s_waitcnt vmcnt(%0)" ::"n"(SV) : "memory");
    else
      asm volatile("s_waitcnt vmcnt(0)" ::: "memory");
    BAR();
  }

  // epilogue. C/D frag: col = lane&15, row = (lane>>4)*4 + e  [m89]
  const int r0 = bm + wr * (BM / 2) + lq * 4;
  const int c0 = bn + wc * (BN / 4);
  if constexpr (EPI == 0) {
    const int mat = bn >> 10;  // uniform per block (BN=256 | 1024)
    const float sc = (mat == 0) ? 0.03125f : 1.0f;
    const float* bias = (mat == 0) ? bq : (mat == 1 ? bk : bv);
    u16* Q = (u16*)out0;
    u16* K = (u16*)out1;
    u16* V = (u16*)out2;
#pragma unroll
    for (int nf = 0; nf < 4; ++nf) {
      const int oc = (c0 + nf * 16 + lr) & 1023;
      const float bb = bias[oc];
      if (mat < 2) {
        u16* dst = (mat == 0) ? Q : K;
#pragma unroll
        for (int mi = 0; mi < MF; ++mi) {
          const int row = r0 + mi * 16;
#pragma unroll
          for (int e = 0; e < 4; ++e)
            dst[(size_t)(row + e) * 1024 + oc] =
                f2bf((acc[mi][nf][e] + bb) * sc);
        }
      } else {
#pragma unroll
        for (int mi = 0; mi < MF; ++mi) {
          const int row = r0 + mi * 16;
          const int bz = row >> 11, s = row & 2047;
          ushort4 pk;
          pk.x = f2bf(acc[mi][nf][0] + bb);
          pk.y = f2bf(acc[mi][nf][1] + bb);
          pk.z = f2bf(acc[mi][nf][2] + bb);
          pk.w = f2bf(acc[mi][nf][3] + bb);
          *(ushort4*)&V[((size_t)bz * 1024 + oc) * 2048 + s] = pk;
        }
      }
    }
  } else if constexpr (EPI == 2) {
    u16* C = (u16*)out0 + (size_t)z * sCz;
#pragma unroll
    for (int nf = 0; nf < 4; ++nf) {
      const int col = c0 + nf * 16 + lr;
#pragma unroll
      for (int mi = 0; mi < MF; ++mi) {
        const int row = r0 + mi * 16;
#pragma unroll
        for (int e = 0; e < 4; ++e)
          C[(size_t)(row + e) * ldc + col] = f2bf(acc[mi][nf][e]);
      }
    }
  } else {
    float* C = (float*)out0 + (size_t)z * sCz;
#pragma unroll
    for (int nf = 0; nf < 4; ++nf) {
      const int col = c0 + nf * 16 + lr;
#pragma unroll
      for (int mi = 0; mi < MF; ++mi) {
        const int row = r0 + mi * 16;
#pragma unroll
        for (int e = 0; e < 4; ++e)
          C[(size_t)(row + e) * ldc + col] = acc[mi][nf][e];
      }
    }
  }
}

// ---------------------------------------------------------------------------
__global__ __launch_bounds__(256) void cvt_x(const float* __restrict__ in,
                                             u16* __restrict__ out) {
  const int i = blockIdx.x * 256 + threadIdx.x;
  const float4 v = ((const float4*)in)[i];
  ushort4 o;
  o.x = f2bf(v.x);
  o.y = f2bf(v.y);
  o.z = f2bf(v.z);
  o.w = f2bf(v.w);
  ((ushort4*)out)[i] = o;
}

// W [1024 in][1024 out] f32 -> Wt [1024 out][1024 in] bf16, z selects q/k/v
__global__ void cvt_wt(const float* __restrict__ Wq,
                       const float* __restrict__ Wk,
                       const float* __restrict__ Wv, u16* __restrict__ Wt) {
  __shared__ float s[32][33];
  const float* W = blockIdx.z == 0 ? Wq : (blockIdx.z == 1 ? Wk : Wv);
  u16* O = Wt + (size_t)blockIdx.z * 1048576;
  const int k0 = blockIdx.y * 32, n0 = blockIdx.x * 32;
  s[threadIdx.y][threadIdx.x] =
      W[(size_t)(k0 + threadIdx.y) * 1024 + n0 + threadIdx.x];
  __syncthreads();
  O[(size_t)(n0 + threadIdx.y) * 1024 + k0 + threadIdx.x] =
      f2bf(s[threadIdx.x][threadIdx.y]);
}

// in-place row softmax over bf16 [4][2048][2048]; one block per row
__global__ __launch_bounds__(256) void softmax_rows(u16* __restrict__ SP) {
  const size_t base = ((size_t)blockIdx.y * 2048 + blockIdx.x) * 2048;
  u16* p = SP + base;
  const int t = threadIdx.x;
  __shared__ float red[4];

  uint4 u = ((const uint4*)p)[t];  // 8 bf16 per thread
  unsigned int uu[4] = {u.x, u.y, u.z, u.w};
  float f[8];
#pragma unroll
  for (int j = 0; j < 4; ++j) {
    f[2 * j] = bf2f(uu[j] & 0xffffu);
    f[2 * j + 1] = __builtin_bit_cast(float, uu[j] & 0xffff0000u);
  }
  float mx = f[0];
#pragma unroll
  for (int i = 1; i < 8; ++i) mx = fmaxf(mx, f[i]);
#pragma unroll
  for (int o = 32; o; o >>= 1) mx = fmaxf(mx, __shfl_xor(mx, o, 64));
  if ((t & 63) == 0) red[t >> 6] = mx;
  __syncthreads();
  mx = fmaxf(fmaxf(red[0], red[1]), fmaxf(red[2], red[3]));
  __syncthreads();

  float e[8];
  float sum = 0.f;
#pragma unroll
  for (int i = 0; i < 8; ++i) {
    e[i] = __expf(f[i] - mx);
    sum += e[i];
  }
#pragma unroll
  for (int o = 32; o; o >>= 1) sum += __shfl_xor(sum, o, 64);
  if ((t & 63) == 0) red[t >> 6] = sum;
  __syncthreads();
  sum = red[0] + red[1] + red[2] + red[3];
  const float inv = 1.0f / sum;

  uint4 ov;
  unsigned int w0[4];
#pragma unroll
  for (int j = 0; j < 4; ++j) {
    unsigned int lo = f2bf(e[2 * j] * inv);
    unsigned int hi = f2bf(e[2 * j + 1] * inv);
    w0[j] = lo | (hi << 16);
  }
  ov.x = w0[0];
  ov.y = w0[1];
  ov.z = w0[2];
  ov.w = w0[3];
  ((uint4*)p)[t] = ov;
}

// ---------------------------------------------------------------------------
extern "C" void kernel_launch(void* const* d_in, const int* in_sizes, int n_in,
                              void* d_out, int out_size, void* d_ws,
                              size_t ws_size, hipStream_t stream) {
  const float* x = (const float*)d_in[0];
  const float* Wq = (const float*)d_in[1];
  const float* bq = (const float*)d_in[2];
  const float* Wk = (const float*)d_in[3];
  const float* bk = (const float*)d_in[4];
  const float* Wv = (const float*)d_in[5];
  const float* bv = (const float*)d_in[6];
  float* out = (float*)d_out;
  char* ws = (char*)d_ws;

  u16* xb = (u16*)ws;                              // 16 MiB [8192][1024]
  u16* Wt = (u16*)(ws + 16777216);                 // 6 MiB  [3072][1024]
  u16* Qb = (u16*)(ws + 23068672);                 // 16 MiB [8192][1024]
  u16* Kb = Qb + 8388608;                          // 16 MiB
  u16* Vt = Kb + 8388608;                          // 16 MiB [4][1024][2048]
  u16* SP = Vt + 8388608;                          // 32 MiB [4][2048][2048]

  // 1) dtype prep
  cvt_x<<<8192, 256, 0, stream>>>(x, xb);
  cvt_wt<<<dim3(32, 32, 3), dim3(32, 32), 0, stream>>>(Wq, Wk, Wv, Wt);

  // 2) fused QKV projection (N=3072; Q scaled 1/32 in epilogue)
  gemm8<256, 256, 0><<<dim3(12, 32, 1), 512, 0, stream>>>(
      xb, Wt, bq, bk, bv, Qb, Kb, Vt, 1024, 0, 0, 0, 0);

  // 3) scores = Qs . K^T  (bf16 out, per batch)
  gemm8<256, 256, 2><<<dim3(8, 8, 4), 512, 0, stream>>>(
      Qb, Kb, nullptr, nullptr, nullptr, SP, nullptr, nullptr, 1024, 2048,
      2097152LL, 2097152LL, 4194304LL);

  // 4) softmax in place
  softmax_rows<<<dim3(2048, 4), 256, 0, stream>>>(SP);

  // 5) out = P . V   (A = P [2048][2048], Bt = Vt [1024][2048])
  gemm8<128, 256, 3><<<dim3(4, 16, 4), 512, 0, stream>>>(
      SP, Vt, nullptr, nullptr, nullptr, out, nullptr, nullptr, 2048, 1024,
      4194304LL, 2097152LL, 2097152LL);
}

// Round 3
// 186.262 us; speedup vs baseline: 1.1593x; 1.0334x over previous
//
#include <hip/hip_runtime.h>
#include <hip/hip_bf16.h>

typedef __attribute__((ext_vector_type(8))) short bf16x8;
typedef __attribute__((ext_vector_type(4))) float f32x4;
typedef unsigned short u16;

__device__ __forceinline__ u16 f2bf(float f) {
  unsigned int u = __builtin_bit_cast(unsigned int, f);
  u += 0x7fffu + ((u >> 16) & 1u);
  return (u16)(u >> 16);
}
__device__ __forceinline__ float bf2f(unsigned int h) {
  unsigned int u = h << 16;
  return __builtin_bit_cast(float, u);
}

__device__ __forceinline__ void gload_lds16(const void* g, void* l) {
  __builtin_amdgcn_global_load_lds(
      (const __attribute__((address_space(1))) void*)g,
      (__attribute__((address_space(3))) void*)l, 16, 0, 0);
}

// ---------------------------------------------------------------------------
// 2-phase/K-tile counted-vmcnt NT GEMM. C[m][n] = sum_k A[m][k]*Bt[n][k].
// Tile 256x128, 512 thr = 8 waves (4 wr x 2 wc), per-wave 64x64.
// BK=64 as 2 k-half units. Triple-buffered staging (A 3x32K, B 3x16K = 144K
// LDS): stage target (t+2)%3 never aliases read bufs t%3,(t+1)%3.
// Phase: reads -> stage -> barrier -> lgkm0+schedbar -> prio1 16xMFMA prio0
// -> [vmcnt(6) at ph1] -> barrier.  LDS [rows][32] bf16 units, 16B-block
// swizzle cb ^= (row>>1)&3 (0-conflict, verified r1/r2).
// EPI 0: fused QKV proj (Q:*1/32+bq, K:+bk, V:+bv transposed to Vt)
// EPI 2: bf16 row-major (scores)    EPI 3: f32 row-major (final out)
// ---------------------------------------------------------------------------
template <int EPI>
__global__ __launch_bounds__(512, 2) void gemm2p(
    const u16* __restrict__ Abase, const u16* __restrict__ Btbase,
    const float* __restrict__ bq, const float* __restrict__ bk,
    const float* __restrict__ bv, void* __restrict__ out0,
    void* __restrict__ out1, void* __restrict__ out2, int Kd, int ldc,
    long long sAz, long long sBz, long long sCz) {
  constexpr int AU = 16384;       // A k-half unit: 256 rows x 32 k x 2B
  constexpr int BU = 8192;        // B k-half unit: 128 rows x 32 k x 2B
  constexpr int ABUF = 2 * AU;    // per-buf A (kh0,kh1)
  constexpr int BBUF = 2 * BU;
  constexpr int BBASE = 3 * ABUF; // 98304
  __shared__ char lds[3 * ABUF + 3 * BBUF];  // 147456 B

  const int tid = threadIdx.x;
  const int w = tid >> 6, l = tid & 63;
  const int wr = w >> 1, wc = w & 1;
  const int lq = l >> 4, lr = l & 15;
  const int bm = blockIdx.y * 256, bn = blockIdx.x * 128;
  const int z = blockIdx.z;
  const u16* A = Abase + (size_t)z * sAz;
  const u16* Bt = Btbase + (size_t)z * sBz;
  const int NT = Kd >> 6;

  // staging source: dest slot tid*16 in a [rows][32] unit; source col-block
  // pre-swizzled so linear LDS + swizzled read match.
  const int sr = tid >> 2;
  const int scb = (tid & 3) ^ ((sr >> 1) & 3);
  const u16* gA = A + (size_t)(bm + sr) * Kd + scb * 8;
  const u16* gA2 = gA + (size_t)128 * Kd;
  const u16* gB = Bt + (size_t)(bn + sr) * Kd + scb * 8;

  auto stageA = [&](int buf, int t) {  // 4 gloads
    const int k0 = t * 64;
    char* d = lds + buf * ABUF + tid * 16;
    gload_lds16(gA + k0, d);
    gload_lds16(gA2 + k0, d + 8192);
    gload_lds16(gA + k0 + 32, d + AU);
    gload_lds16(gA2 + k0 + 32, d + AU + 8192);
  };
  auto stageB = [&](int buf, int t) {  // 2 gloads
    const int k0 = t * 64;
    char* d = lds + BBASE + buf * BBUF + tid * 16;
    gload_lds16(gB + k0, d);
    gload_lds16(gB + k0 + 32, d + BU);
  };

  const int swz = ((lq ^ (lr >> 1)) & 3) << 4;
  const int offA = (wr * 64 + lr) * 64 + swz;
  const int offB = (wc * 64 + lr) * 64 + swz;

  f32x4 acc[4][4] = {};
  bf16x8 aR[4][2];      // [m-frag][kh]
  bf16x8 bR[2][2][2];   // [nh][kh][ni]

  auto rdA = [&](int rbuf) {
    const char* base = lds + rbuf * ABUF + offA;
#pragma unroll
    for (int mi = 0; mi < 4; ++mi)
#pragma unroll
      for (int kh = 0; kh < 2; ++kh)
        aR[mi][kh] = *(const bf16x8*)(base + kh * AU + mi * 1024);
  };
  auto rdB = [&](int rbuf, int nh) {
    const char* base = lds + BBASE + rbuf * BBUF + offB;
#pragma unroll
    for (int kh = 0; kh < 2; ++kh)
#pragma unroll
      for (int ni = 0; ni < 2; ++ni)
        bR[nh][kh][ni] =
            *(const bf16x8*)(base + kh * BU + (nh * 2 + ni) * 1024);
  };
  auto mma = [&](int nh) {
    __builtin_amdgcn_s_setprio(1);
#pragma unroll
    for (int kh = 0; kh < 2; ++kh)
#pragma unroll
      for (int mi = 0; mi < 4; ++mi)
#pragma unroll
        for (int ni = 0; ni < 2; ++ni)
          acc[mi][nh * 2 + ni] = __builtin_amdgcn_mfma_f32_16x16x32_bf16(
              aR[mi][kh], bR[nh][kh][ni], acc[mi][nh * 2 + ni], 0, 0, 0);
    __builtin_amdgcn_s_setprio(0);
  };

  // prologue: stage t0, t1 (12 loads); wait for t0's 6.
  stageA(0, 0);
  stageB(0, 0);
  stageA(1, 1);
  stageB(1, 1);
  asm volatile("s_waitcnt vmcnt(6)" ::: "memory");
  __builtin_amdgcn_s_barrier();

  int rbuf = 0, sbuf = 2;
  for (int t = 0; t < NT; ++t) {
    // ---- ph0: quadrant nh=0 ----
    rdA(rbuf);
    rdB(rbuf, 0);
    if (t + 2 < NT) stageA(sbuf, t + 2);
    asm volatile("s_waitcnt lgkmcnt(8)" ::: "memory");
    __builtin_amdgcn_s_barrier();
    asm volatile("s_waitcnt lgkmcnt(0)" ::: "memory");
    __builtin_amdgcn_sched_barrier(0);
    mma(0);
    __builtin_amdgcn_s_barrier();
    // ---- ph1: quadrant nh=1 ----
    rdB(rbuf, 1);
    if (t + 2 < NT) stageB(sbuf, t + 2);
    __builtin_amdgcn_s_barrier();
    asm volatile("s_waitcnt lgkmcnt(0)" ::: "memory");
    __builtin_amdgcn_sched_barrier(0);
    mma(1);
    if (t + 3 <= NT)
      asm volatile("s_waitcnt vmcnt(6)" ::: "memory");
    else
      asm volatile("s_waitcnt vmcnt(0)" ::: "memory");
    __builtin_amdgcn_s_barrier();
    rbuf = (rbuf == 2) ? 0 : rbuf + 1;
    sbuf = (sbuf == 2) ? 0 : sbuf + 1;
  }

  // epilogue. C/D frag: col = lane&15, row = (lane>>4)*4 + e  [m89]
  const int r0 = bm + wr * 64 + lq * 4;
  const int c0 = bn + wc * 64;
  if constexpr (EPI == 0) {
    const int mat = bn >> 10;  // uniform per block (128 | 1024)
    const float sc = (mat == 0) ? 0.03125f : 1.0f;
    const float* bias = (mat == 0) ? bq : (mat == 1 ? bk : bv);
    u16* Q = (u16*)out0;
    u16* K = (u16*)out1;
    u16* V = (u16*)out2;
#pragma unroll
    for (int nf = 0; nf < 4; ++nf) {
      const int oc = (c0 & 1023) + nf * 16 + lr;
      const float bb = bias[oc];
      if (mat < 2) {
        u16* dst = (mat == 0) ? Q : K;
#pragma unroll
        for (int mi = 0; mi < 4; ++mi) {
          const int row = r0 + mi * 16;
#pragma unroll
          for (int e = 0; e < 4; ++e)
            dst[(size_t)(row + e) * 1024 + oc] =
                f2bf((acc[mi][nf][e] + bb) * sc);
        }
      } else {
#pragma unroll
        for (int mi = 0; mi < 4; ++mi) {
          const int row = r0 + mi * 16;
          const int bz = row >> 11, s = row & 2047;
          ushort4 pk;
          pk.x = f2bf(acc[mi][nf][0] + bb);
          pk.y = f2bf(acc[mi][nf][1] + bb);
          pk.z = f2bf(acc[mi][nf][2] + bb);
          pk.w = f2bf(acc[mi][nf][3] + bb);
          *(ushort4*)&V[((size_t)bz * 1024 + oc) * 2048 + s] = pk;
        }
      }
    }
  } else if constexpr (EPI == 2) {
    u16* C = (u16*)out0 + (size_t)z * sCz;
#pragma unroll
    for (int nf = 0; nf < 4; ++nf) {
      const int col = c0 + nf * 16 + lr;
#pragma unroll
      for (int mi = 0; mi < 4; ++mi) {
        const int row = r0 + mi * 16;
#pragma unroll
        for (int e = 0; e < 4; ++e)
          C[(size_t)(row + e) * ldc + col] = f2bf(acc[mi][nf][e]);
      }
    }
  } else {
    float* C = (float*)out0 + (size_t)z * sCz;
#pragma unroll
    for (int nf = 0; nf < 4; ++nf) {
      const int col = c0 + nf * 16 + lr;
#pragma unroll
      for (int mi = 0; mi < 4; ++mi) {
        const int row = r0 + mi * 16;
#pragma unroll
        for (int e = 0; e < 4; ++e)
          C[(size_t)(row + e) * ldc + col] = acc[mi][nf][e];
      }
    }
  }
}

// ---------------------------------------------------------------------------
__global__ __launch_bounds__(256) void cvt_x(const float* __restrict__ in,
                                             u16* __restrict__ out) {
  const int i = blockIdx.x * 256 + threadIdx.x;
  const float4 v = ((const float4*)in)[i];
  ushort4 o;
  o.x = f2bf(v.x);
  o.y = f2bf(v.y);
  o.z = f2bf(v.z);
  o.w = f2bf(v.w);
  ((ushort4*)out)[i] = o;
}

// W [1024 in][1024 out] f32 -> Wt [1024 out][1024 in] bf16, z selects q/k/v
__global__ void cvt_wt(const float* __restrict__ Wq,
                       const float* __restrict__ Wk,
                       const float* __restrict__ Wv, u16* __restrict__ Wt) {
  __shared__ float s[32][33];
  const float* W = blockIdx.z == 0 ? Wq : (blockIdx.z == 1 ? Wk : Wv);
  u16* O = Wt + (size_t)blockIdx.z * 1048576;
  const int k0 = blockIdx.y * 32, n0 = blockIdx.x * 32;
  s[threadIdx.y][threadIdx.x] =
      W[(size_t)(k0 + threadIdx.y) * 1024 + n0 + threadIdx.x];
  __syncthreads();
  O[(size_t)(n0 + threadIdx.y) * 1024 + k0 + threadIdx.x] =
      f2bf(s[threadIdx.x][threadIdx.y]);
}

// in-place row softmax over bf16 [4][2048][2048]; one block per row
__global__ __launch_bounds__(256) void softmax_rows(u16* __restrict__ SP) {
  const size_t base = ((size_t)blockIdx.y * 2048 + blockIdx.x) * 2048;
  u16* p = SP + base;
  const int t = threadIdx.x;
  __shared__ float red[4];

  uint4 u = ((const uint4*)p)[t];  // 8 bf16 per thread
  unsigned int uu[4] = {u.x, u.y, u.z, u.w};
  float f[8];
#pragma unroll
  for (int j = 0; j < 4; ++j) {
    f[2 * j] = bf2f(uu[j] & 0xffffu);
    f[2 * j + 1] = __builtin_bit_cast(float, uu[j] & 0xffff0000u);
  }
  float mx = f[0];
#pragma unroll
  for (int i = 1; i < 8; ++i) mx = fmaxf(mx, f[i]);
#pragma unroll
  for (int o = 32; o; o >>= 1) mx = fmaxf(mx, __shfl_xor(mx, o, 64));
  if ((t & 63) == 0) red[t >> 6] = mx;
  __syncthreads();
  mx = fmaxf(fmaxf(red[0], red[1]), fmaxf(red[2], red[3]));
  __syncthreads();

  float e[8];
  float sum = 0.f;
#pragma unroll
  for (int i = 0; i < 8; ++i) {
    e[i] = __expf(f[i] - mx);
    sum += e[i];
  }
#pragma unroll
  for (int o = 32; o; o >>= 1) sum += __shfl_xor(sum, o, 64);
  if ((t & 63) == 0) red[t >> 6] = sum;
  __syncthreads();
  sum = red[0] + red[1] + red[2] + red[3];
  const float inv = 1.0f / sum;

  uint4 ov;
  unsigned int w0[4];
#pragma unroll
  for (int j = 0; j < 4; ++j) {
    unsigned int lo = f2bf(e[2 * j] * inv);
    unsigned int hi = f2bf(e[2 * j + 1] * inv);
    w0[j] = lo | (hi << 16);
  }
  ov.x = w0[0];
  ov.y = w0[1];
  ov.z = w0[2];
  ov.w = w0[3];
  ((uint4*)p)[t] = ov;
}

// ---------------------------------------------------------------------------
extern "C" void kernel_launch(void* const* d_in, const int* in_sizes, int n_in,
                              void* d_out, int out_size, void* d_ws,
                              size_t ws_size, hipStream_t stream) {
  const float* x = (const float*)d_in[0];
  const float* Wq = (const float*)d_in[1];
  const float* bq = (const float*)d_in[2];
  const float* Wk = (const float*)d_in[3];
  const float* bk = (const float*)d_in[4];
  const float* Wv = (const float*)d_in[5];
  const float* bv = (const float*)d_in[6];
  float* out = (float*)d_out;
  char* ws = (char*)d_ws;

  u16* xb = (u16*)ws;                    // 16 MiB [8192][1024]
  u16* Wt = (u16*)(ws + 16777216);       // 6 MiB  [3072][1024]
  u16* Qb = (u16*)(ws + 23068672);       // 16 MiB [8192][1024]
  u16* Kb = Qb + 8388608;                // 16 MiB
  u16* Vt = Kb + 8388608;                // 16 MiB [4][1024][2048]
  u16* SP = Vt + 8388608;                // 32 MiB [4][2048][2048]

  // 1) dtype prep
  cvt_x<<<8192, 256, 0, stream>>>(x, xb);
  cvt_wt<<<dim3(32, 32, 3), dim3(32, 32), 0, stream>>>(Wq, Wk, Wv, Wt);

  // 2) fused QKV projection (N=3072; Q scaled 1/32 in epilogue)
  gemm2p<0><<<dim3(24, 32, 1), 512, 0, stream>>>(
      xb, Wt, bq, bk, bv, Qb, Kb, Vt, 1024, 0, 0, 0, 0);

  // 3) scores = Qs . K^T  (bf16 out, per batch)
  gemm2p<2><<<dim3(16, 8, 4), 512, 0, stream>>>(
      Qb, Kb, nullptr, nullptr, nullptr, SP, nullptr, nullptr, 1024, 2048,
      2097152LL, 2097152LL, 4194304LL);

  // 4) softmax in place
  softmax_rows<<<dim3(2048, 4), 256, 0, stream>>>(SP);

  // 5) out = P . V   (A = P [2048][2048], Bt = Vt [1024][2048])
  gemm2p<3><<<dim3(8, 8, 4), 512, 0, stream>>>(
      SP, Vt, nullptr, nullptr, nullptr, out, nullptr, nullptr, 2048, 1024,
      4194304LL, 2097152LL, 2097152LL);
}